// Round 1
// baseline (6797.543 us; speedup 1.0000x reference)
//
#include <hip/hip_runtime.h>

// LightGCN 2-layer propagation on MI355X.
//
// reference:
//   x0 = concat(user_emb, item_emb)            [150000, 64] f32
//   for 2 layers: x = 0.5 * (scatter_add(row, x[col]) + scatter_add(col, x[row]))
//
// R1 strategy: atomic scatter-add baseline.
//   - layer 1 gathers straight from user/item tables (no concat copy)
//   - y1 lives in d_ws (38.4 MB), zeroed via hipMemsetAsync each call
//   - 16 lanes/edge, float4/lane: 256 B coalesced gather per endpoint,
//     4 f32 atomicAdds per lane (device-scope by default, cross-XCD safe)

#define NUM_USERS 100000
#define NUM_ITEMS 50000
#define N_NODES   150000
#define NUM_EDGES 2000000
#define EMB_D     64

// ---- layer 1: gather from split user/item tables, scatter 0.5*x into y ----
__global__ __launch_bounds__(256) void lightgcn_scatter1(
    const int* __restrict__ eidx,       // [2, NUM_EDGES] int32
    const float* __restrict__ user,     // [NUM_USERS, 64]
    const float* __restrict__ item,     // [NUM_ITEMS, 64]
    float* __restrict__ y)              // [N_NODES, 64] accumulator (pre-zeroed)
{
    int gid = blockIdx.x * blockDim.x + threadIdx.x;
    int e = gid >> 4;                   // 16 threads per edge
    if (e >= NUM_EDGES) return;
    int q = (gid & 15) << 2;            // dim offset: 0,4,...,60

    int row = eidx[e];
    int col = eidx[NUM_EDGES + e];

    const float* xr = (row < NUM_USERS)
        ? (user + (size_t)row * EMB_D)
        : (item + (size_t)(row - NUM_USERS) * EMB_D);
    const float* xc = (col < NUM_USERS)
        ? (user + (size_t)col * EMB_D)
        : (item + (size_t)(col - NUM_USERS) * EMB_D);

    float4 vc = *(const float4*)(xc + q);
    float4 vr = *(const float4*)(xr + q);

    float* yr = y + (size_t)row * EMB_D + q;
    float* yc = y + (size_t)col * EMB_D + q;

    atomicAdd(yr + 0, 0.5f * vc.x);
    atomicAdd(yr + 1, 0.5f * vc.y);
    atomicAdd(yr + 2, 0.5f * vc.z);
    atomicAdd(yr + 3, 0.5f * vc.w);

    atomicAdd(yc + 0, 0.5f * vr.x);
    atomicAdd(yc + 1, 0.5f * vr.y);
    atomicAdd(yc + 2, 0.5f * vr.z);
    atomicAdd(yc + 3, 0.5f * vr.w);
}

// ---- layer 2: gather from y1, scatter 0.5*y1 into out ----
__global__ __launch_bounds__(256) void lightgcn_scatter2(
    const int* __restrict__ eidx,
    const float* __restrict__ x,        // [N_NODES, 64] = layer-1 output
    float* __restrict__ out)            // [N_NODES, 64] accumulator (pre-zeroed)
{
    int gid = blockIdx.x * blockDim.x + threadIdx.x;
    int e = gid >> 4;
    if (e >= NUM_EDGES) return;
    int q = (gid & 15) << 2;

    int row = eidx[e];
    int col = eidx[NUM_EDGES + e];

    float4 vc = *(const float4*)(x + (size_t)col * EMB_D + q);
    float4 vr = *(const float4*)(x + (size_t)row * EMB_D + q);

    float* yr = out + (size_t)row * EMB_D + q;
    float* yc = out + (size_t)col * EMB_D + q;

    atomicAdd(yr + 0, 0.5f * vc.x);
    atomicAdd(yr + 1, 0.5f * vc.y);
    atomicAdd(yr + 2, 0.5f * vc.z);
    atomicAdd(yr + 3, 0.5f * vc.w);

    atomicAdd(yc + 0, 0.5f * vr.x);
    atomicAdd(yc + 1, 0.5f * vr.y);
    atomicAdd(yc + 2, 0.5f * vr.z);
    atomicAdd(yc + 3, 0.5f * vr.w);
}

extern "C" void kernel_launch(void* const* d_in, const int* in_sizes, int n_in,
                              void* d_out, int out_size, void* d_ws, size_t ws_size,
                              hipStream_t stream) {
    const int*   eidx = (const int*)d_in[0];     // [2, NUM_EDGES]
    const float* user = (const float*)d_in[1];   // [NUM_USERS, 64]
    const float* item = (const float*)d_in[2];   // [NUM_ITEMS, 64]
    float*       out  = (float*)d_out;           // [N_NODES, 64]
    float*       y1   = (float*)d_ws;            // [N_NODES, 64] scratch

    const size_t node_bytes = (size_t)N_NODES * EMB_D * sizeof(float);  // 38.4 MB

    // Zero accumulators (harness poisons d_ws/d_out to 0xAA before every call).
    hipMemsetAsync(y1, 0, node_bytes, stream);
    hipMemsetAsync(out, 0, node_bytes, stream);

    const int threads_per_edge = 16;
    const int block = 256;
    const long long total = (long long)NUM_EDGES * threads_per_edge;
    const int grid = (int)((total + block - 1) / block);

    lightgcn_scatter1<<<grid, block, 0, stream>>>(eidx, user, item, y1);
    lightgcn_scatter2<<<grid, block, 0, stream>>>(eidx, y1, out);
}

// Round 3
// 950.429 us; speedup vs baseline: 7.1521x; 7.1521x over previous
//
#include <hip/hip_runtime.h>

// LightGCN 2-layer propagation on MI355X — R3: CSR gather within 38.4 MB ws.
//
// R2 post-mortem: core dump, almost certainly ws overflow (R2 needed ~56 MB;
// R1 only proved ws_size >= 38.4 MB). R3 fits ws in ~36.4 MB:
//   - adj 16 MB + deg 0.6 MB + cursor 0.6 MB (start = cursor_end - deg)
//   - y1 (layer-1 output, f32) lives in d_out
//   - layer 2 done per 32-column half into a 19.2 MB ws buffer, then copied
//     into d_out (gather is per-dim independent, so half A of y2 only needs
//     half A of y1; y1 half is dead once its y2 half is written)
// No f32 atomics anywhere (R1 showed atomic write-through = 4 GB WRITE_SIZE).

#define NUM_USERS 100000
#define NUM_ITEMS 50000
#define N_NODES   150000
#define NUM_EDGES 2000000
#define EMB_D     64

#define SCAN_T 256
#define SCAN_E 1024
#define NBLK   ((N_NODES + SCAN_E - 1) / SCAN_E)   // 147

// ---- 1) degree histogram ----
__global__ __launch_bounds__(256) void k_hist(const int* __restrict__ eidx,
                                              int* __restrict__ deg) {
    int e = blockIdx.x * blockDim.x + threadIdx.x;
    if (e >= NUM_EDGES) return;
    int r = eidx[e];
    int c = eidx[NUM_EDGES + e];
    atomicAdd(&deg[r], 1);
    atomicAdd(&deg[c], 1);
}

// ---- 2a) per-block exclusive scan of deg -> cur, block totals ----
__global__ __launch_bounds__(SCAN_T) void k_scan_local(const int* __restrict__ deg,
                                                       int* __restrict__ cur,
                                                       int* __restrict__ blocksums) {
    __shared__ int lds[SCAN_T];
    int base = blockIdx.x * SCAN_E + threadIdx.x * 4;
    int v[4];
#pragma unroll
    for (int k = 0; k < 4; ++k) {
        int i = base + k;
        v[k] = (i < N_NODES) ? deg[i] : 0;
    }
    int t = v[0] + v[1] + v[2] + v[3];

    lds[threadIdx.x] = t;
    __syncthreads();
    int val = t;
    for (int off = 1; off < SCAN_T; off <<= 1) {
        int add = (threadIdx.x >= off) ? lds[threadIdx.x - off] : 0;
        __syncthreads();
        val += add;
        lds[threadIdx.x] = val;
        __syncthreads();
    }
    int run = val - t;   // exclusive prefix for this thread's first element
#pragma unroll
    for (int k = 0; k < 4; ++k) {
        int i = base + k;
        if (i < N_NODES) cur[i] = run;
        run += v[k];
    }
    if (threadIdx.x == SCAN_T - 1) blocksums[blockIdx.x] = val;
}

// ---- 2b) single-block exclusive scan of 147 block sums ----
__global__ __launch_bounds__(SCAN_T) void k_scan_partials(const int* __restrict__ blocksums,
                                                          int* __restrict__ blockoffs) {
    __shared__ int lds[SCAN_T];
    int t = (threadIdx.x < NBLK) ? blocksums[threadIdx.x] : 0;
    lds[threadIdx.x] = t;
    __syncthreads();
    int val = t;
    for (int off = 1; off < SCAN_T; off <<= 1) {
        int add = (threadIdx.x >= off) ? lds[threadIdx.x - off] : 0;
        __syncthreads();
        val += add;
        lds[threadIdx.x] = val;
        __syncthreads();
    }
    if (threadIdx.x < NBLK) blockoffs[threadIdx.x] = val - t;
}

// ---- 2c) add block offsets into cur ----
__global__ __launch_bounds__(256) void k_scan_add(int* __restrict__ cur,
                                                  const int* __restrict__ blockoffs) {
    int i = blockIdx.x * blockDim.x + threadIdx.x;
    if (i >= N_NODES) return;
    cur[i] += blockoffs[i / SCAN_E];
}

// ---- 3) fill adjacency; afterwards cur[n] = end offset of node n ----
__global__ __launch_bounds__(256) void k_fill(const int* __restrict__ eidx,
                                              int* __restrict__ cur,
                                              int* __restrict__ adj) {
    int e = blockIdx.x * blockDim.x + threadIdx.x;
    if (e >= NUM_EDGES) return;
    int r = eidx[e];
    int c = eidx[NUM_EDGES + e];
    int p = atomicAdd(&cur[r], 1);
    adj[p] = c;
    int q = atomicAdd(&cur[c], 1);
    adj[q] = r;
}

// ---- 4) layer-1 gather: one 64-lane wave per node, lane = dim ----
__global__ __launch_bounds__(256) void k_gather64(const int* __restrict__ adj,
                                                  const int* __restrict__ cur,
                                                  const int* __restrict__ deg,
                                                  const float* __restrict__ user,
                                                  const float* __restrict__ item,
                                                  float* __restrict__ out) {
    int wid = (blockIdx.x * blockDim.x + threadIdx.x) >> 6;   // node
    int lane = threadIdx.x & 63;                              // dim
    if (wid >= N_NODES) return;

    int end = cur[wid];
    int start = end - deg[wid];
    float acc = 0.f;

    int j = start;
    for (; j + 4 <= end; j += 4) {
        int n0 = adj[j + 0], n1 = adj[j + 1], n2 = adj[j + 2], n3 = adj[j + 3];
        const float* p0 = (n0 < NUM_USERS) ? user + (size_t)n0 * EMB_D
                                           : item + (size_t)(n0 - NUM_USERS) * EMB_D;
        const float* p1 = (n1 < NUM_USERS) ? user + (size_t)n1 * EMB_D
                                           : item + (size_t)(n1 - NUM_USERS) * EMB_D;
        const float* p2 = (n2 < NUM_USERS) ? user + (size_t)n2 * EMB_D
                                           : item + (size_t)(n2 - NUM_USERS) * EMB_D;
        const float* p3 = (n3 < NUM_USERS) ? user + (size_t)n3 * EMB_D
                                           : item + (size_t)(n3 - NUM_USERS) * EMB_D;
        acc += p0[lane];
        acc += p1[lane];
        acc += p2[lane];
        acc += p3[lane];
    }
    for (; j < end; ++j) {
        int n = adj[j];
        const float* p = (n < NUM_USERS) ? user + (size_t)n * EMB_D
                                         : item + (size_t)(n - NUM_USERS) * EMB_D;
        acc += p[lane];
    }
    out[(size_t)wid * EMB_D + lane] = 0.5f * acc;
}

// ---- 5) layer-2 half gather: 32 lanes per node (2 nodes per wave) ----
// halfout[n*32 + d] = 0.5 * sum_nbr x[nbr*64 + coloff + d]
__global__ __launch_bounds__(256) void k_gather_half(const int* __restrict__ adj,
                                                     const int* __restrict__ cur,
                                                     const int* __restrict__ deg,
                                                     const float* __restrict__ x,
                                                     int coloff,
                                                     float* __restrict__ halfout) {
    int gid = blockIdx.x * blockDim.x + threadIdx.x;
    int node = gid >> 5;
    int d = gid & 31;
    if (node >= N_NODES) return;

    int end = cur[node];
    int start = end - deg[node];
    float acc = 0.f;

    int j = start;
    for (; j + 4 <= end; j += 4) {
        int n0 = adj[j + 0], n1 = adj[j + 1], n2 = adj[j + 2], n3 = adj[j + 3];
        acc += x[(size_t)n0 * EMB_D + coloff + d];
        acc += x[(size_t)n1 * EMB_D + coloff + d];
        acc += x[(size_t)n2 * EMB_D + coloff + d];
        acc += x[(size_t)n3 * EMB_D + coloff + d];
    }
    for (; j < end; ++j) {
        int n = adj[j];
        acc += x[(size_t)n * EMB_D + coloff + d];
    }
    halfout[(size_t)node * 32 + d] = 0.5f * acc;
}

// ---- 6) copy half buffer [N,32] into d_out columns [coloff, coloff+32) ----
__global__ __launch_bounds__(256) void k_copy_half(const float* __restrict__ half,
                                                   float* __restrict__ out,
                                                   int coloff) {
    int gid = blockIdx.x * blockDim.x + threadIdx.x;   // one per float4
    const int total = N_NODES * 32 / 4;                // 1.2M
    if (gid >= total) return;
    int node = gid >> 3;           // 8 float4 per 32-col row
    int q = (gid & 7) * 4;
    float4 v = *(const float4*)(half + (size_t)node * 32 + q);
    *(float4*)(out + (size_t)node * EMB_D + coloff + q) = v;
}

extern "C" void kernel_launch(void* const* d_in, const int* in_sizes, int n_in,
                              void* d_out, int out_size, void* d_ws, size_t ws_size,
                              hipStream_t stream) {
    const int*   eidx = (const int*)d_in[0];     // [2, NUM_EDGES] int32
    const float* user = (const float*)d_in[1];   // [NUM_USERS, 64]
    const float* item = (const float*)d_in[2];   // [NUM_ITEMS, 64]
    float*       out  = (float*)d_out;           // [N_NODES, 64]

    // workspace layout — total ~36.4 MB (R1 proved ws_size >= 38.4 MB)
    char* ws = (char*)d_ws;
    size_t off = 0;
    auto alloc = [&](size_t bytes) {
        char* p = ws + off;
        off += (bytes + 255) & ~(size_t)255;
        return p;
    };
    int*   adj       = (int*)alloc((size_t)4 * NUM_EDGES * sizeof(int));   // 16 MB
    int*   deg       = (int*)alloc((size_t)N_NODES * sizeof(int));         // 0.6 MB
    int*   cur       = (int*)alloc((size_t)N_NODES * sizeof(int));         // 0.6 MB
    int*   blocksums = (int*)alloc((size_t)SCAN_T * sizeof(int));
    int*   blockoffs = (int*)alloc((size_t)SCAN_T * sizeof(int));
    float* half      = (float*)alloc((size_t)N_NODES * 32 * sizeof(float)); // 19.2 MB

    hipMemsetAsync(deg, 0, (size_t)N_NODES * sizeof(int), stream);

    const int B = 256;
    const int edge_grid = (NUM_EDGES + B - 1) / B;
    const int node_grid = (N_NODES + B - 1) / B;

    // build CSR
    k_hist<<<edge_grid, B, 0, stream>>>(eidx, deg);
    k_scan_local<<<NBLK, SCAN_T, 0, stream>>>(deg, cur, blocksums);
    k_scan_partials<<<1, SCAN_T, 0, stream>>>(blocksums, blockoffs);
    k_scan_add<<<node_grid, B, 0, stream>>>(cur, blockoffs);
    k_fill<<<edge_grid, B, 0, stream>>>(eidx, cur, adj);

    // layer 1: y1 (f32) -> d_out
    const int g64 = ((N_NODES * 64) + B - 1) / B;          // 37500 blocks
    k_gather64<<<g64, B, 0, stream>>>(adj, cur, deg, user, item, out);

    // layer 2, per 32-column half: gather from d_out half -> ws, copy back
    const int g32 = ((N_NODES * 32) + B - 1) / B;          // 18750 blocks
    const int gcp = ((N_NODES * 32 / 4) + B - 1) / B;      // 4688 blocks

    k_gather_half<<<g32, B, 0, stream>>>(adj, cur, deg, out, 0, half);
    k_copy_half<<<gcp, B, 0, stream>>>(half, out, 0);
    k_gather_half<<<g32, B, 0, stream>>>(adj, cur, deg, out, 32, half);
    k_copy_half<<<gcp, B, 0, stream>>>(half, out, 32);
}

// Round 4
// 932.219 us; speedup vs baseline: 7.2918x; 1.0195x over previous
//
#include <hip/hip_runtime.h>

// LightGCN 2-layer propagation on MI355X — R4: ILP on the scatter atomics.
//
// R3 post-mortem: k_fill = 378 us (40%), VALUBusy 0.2%, HBM 8.6% -> pure
// latency-bound on two SERIALLY DEPENDENT returning atomicAdds per thread.
// R4: issue all returning atomics before using any result; 2 edges/thread in
// fill (4 outstanding atomics), 4 edges/thread in hist (no-return atomics).
// Everything else (CSR layout, gather structure, ws budget ~36.4 MB) as R3.

#define NUM_USERS 100000
#define NUM_ITEMS 50000
#define N_NODES   150000
#define NUM_EDGES 2000000
#define EMB_D     64

#define SCAN_T 256
#define SCAN_E 1024
#define NBLK   ((N_NODES + SCAN_E - 1) / SCAN_E)   // 147

// ---- 1) degree histogram: 4 edges per thread, fire-and-forget atomics ----
__global__ __launch_bounds__(256) void k_hist(const int* __restrict__ eidx,
                                              int* __restrict__ deg) {
    const int Q = NUM_EDGES / 4;                  // 500000
    int t = blockIdx.x * blockDim.x + threadIdx.x;
    if (t >= Q) return;
    int e0 = t, e1 = t + Q, e2 = t + 2 * Q, e3 = t + 3 * Q;
    int r0 = eidx[e0], r1 = eidx[e1], r2 = eidx[e2], r3 = eidx[e3];
    int c0 = eidx[NUM_EDGES + e0], c1 = eidx[NUM_EDGES + e1];
    int c2 = eidx[NUM_EDGES + e2], c3 = eidx[NUM_EDGES + e3];
    atomicAdd(&deg[r0], 1);
    atomicAdd(&deg[c0], 1);
    atomicAdd(&deg[r1], 1);
    atomicAdd(&deg[c1], 1);
    atomicAdd(&deg[r2], 1);
    atomicAdd(&deg[c2], 1);
    atomicAdd(&deg[r3], 1);
    atomicAdd(&deg[c3], 1);
}

// ---- 2a) per-block exclusive scan of deg -> cur, block totals ----
__global__ __launch_bounds__(SCAN_T) void k_scan_local(const int* __restrict__ deg,
                                                       int* __restrict__ cur,
                                                       int* __restrict__ blocksums) {
    __shared__ int lds[SCAN_T];
    int base = blockIdx.x * SCAN_E + threadIdx.x * 4;
    int v[4];
#pragma unroll
    for (int k = 0; k < 4; ++k) {
        int i = base + k;
        v[k] = (i < N_NODES) ? deg[i] : 0;
    }
    int t = v[0] + v[1] + v[2] + v[3];

    lds[threadIdx.x] = t;
    __syncthreads();
    int val = t;
    for (int off = 1; off < SCAN_T; off <<= 1) {
        int add = (threadIdx.x >= off) ? lds[threadIdx.x - off] : 0;
        __syncthreads();
        val += add;
        lds[threadIdx.x] = val;
        __syncthreads();
    }
    int run = val - t;
#pragma unroll
    for (int k = 0; k < 4; ++k) {
        int i = base + k;
        if (i < N_NODES) cur[i] = run;
        run += v[k];
    }
    if (threadIdx.x == SCAN_T - 1) blocksums[blockIdx.x] = val;
}

// ---- 2b) single-block exclusive scan of 147 block sums ----
__global__ __launch_bounds__(SCAN_T) void k_scan_partials(const int* __restrict__ blocksums,
                                                          int* __restrict__ blockoffs) {
    __shared__ int lds[SCAN_T];
    int t = (threadIdx.x < NBLK) ? blocksums[threadIdx.x] : 0;
    lds[threadIdx.x] = t;
    __syncthreads();
    int val = t;
    for (int off = 1; off < SCAN_T; off <<= 1) {
        int add = (threadIdx.x >= off) ? lds[threadIdx.x - off] : 0;
        __syncthreads();
        val += add;
        lds[threadIdx.x] = val;
        __syncthreads();
    }
    if (threadIdx.x < NBLK) blockoffs[threadIdx.x] = val - t;
}

// ---- 2c) add block offsets into cur ----
__global__ __launch_bounds__(256) void k_scan_add(int* __restrict__ cur,
                                                  const int* __restrict__ blockoffs) {
    int i = blockIdx.x * blockDim.x + threadIdx.x;
    if (i >= N_NODES) return;
    cur[i] += blockoffs[i / SCAN_E];
}

// ---- 3) fill adjacency: 2 edges/thread, 4 returning atomics in flight ----
__global__ __launch_bounds__(256) void k_fill(const int* __restrict__ eidx,
                                              int* __restrict__ cur,
                                              int* __restrict__ adj) {
    const int H = NUM_EDGES / 2;                  // 1000000
    int t = blockIdx.x * blockDim.x + threadIdx.x;
    if (t >= H) return;
    int e0 = t, e1 = t + H;
    int r0 = eidx[e0], r1 = eidx[e1];
    int c0 = eidx[NUM_EDGES + e0], c1 = eidx[NUM_EDGES + e1];

    // all four returning atomics issued before any result is consumed
    int p0 = atomicAdd(&cur[r0], 1);
    int q0 = atomicAdd(&cur[c0], 1);
    int p1 = atomicAdd(&cur[r1], 1);
    int q1 = atomicAdd(&cur[c1], 1);

    adj[p0] = c0;
    adj[q0] = r0;
    adj[p1] = c1;
    adj[q1] = r1;
}

// ---- 4) layer-1 gather: one 64-lane wave per node, lane = dim ----
__global__ __launch_bounds__(256) void k_gather64(const int* __restrict__ adj,
                                                  const int* __restrict__ cur,
                                                  const int* __restrict__ deg,
                                                  const float* __restrict__ user,
                                                  const float* __restrict__ item,
                                                  float* __restrict__ out) {
    int wid = (blockIdx.x * blockDim.x + threadIdx.x) >> 6;   // node
    int lane = threadIdx.x & 63;                              // dim
    if (wid >= N_NODES) return;

    int end = cur[wid];
    int start = end - deg[wid];
    float acc = 0.f;

    int j = start;
    for (; j + 4 <= end; j += 4) {
        int n0 = adj[j + 0], n1 = adj[j + 1], n2 = adj[j + 2], n3 = adj[j + 3];
        const float* p0 = (n0 < NUM_USERS) ? user + (size_t)n0 * EMB_D
                                           : item + (size_t)(n0 - NUM_USERS) * EMB_D;
        const float* p1 = (n1 < NUM_USERS) ? user + (size_t)n1 * EMB_D
                                           : item + (size_t)(n1 - NUM_USERS) * EMB_D;
        const float* p2 = (n2 < NUM_USERS) ? user + (size_t)n2 * EMB_D
                                           : item + (size_t)(n2 - NUM_USERS) * EMB_D;
        const float* p3 = (n3 < NUM_USERS) ? user + (size_t)n3 * EMB_D
                                           : item + (size_t)(n3 - NUM_USERS) * EMB_D;
        acc += p0[lane];
        acc += p1[lane];
        acc += p2[lane];
        acc += p3[lane];
    }
    for (; j < end; ++j) {
        int n = adj[j];
        const float* p = (n < NUM_USERS) ? user + (size_t)n * EMB_D
                                         : item + (size_t)(n - NUM_USERS) * EMB_D;
        acc += p[lane];
    }
    out[(size_t)wid * EMB_D + lane] = 0.5f * acc;
}

// ---- 5) layer-2 half gather: 32 lanes per node (2 nodes per wave) ----
__global__ __launch_bounds__(256) void k_gather_half(const int* __restrict__ adj,
                                                     const int* __restrict__ cur,
                                                     const int* __restrict__ deg,
                                                     const float* __restrict__ x,
                                                     int coloff,
                                                     float* __restrict__ halfout) {
    int gid = blockIdx.x * blockDim.x + threadIdx.x;
    int node = gid >> 5;
    int d = gid & 31;
    if (node >= N_NODES) return;

    int end = cur[node];
    int start = end - deg[node];
    float acc = 0.f;

    int j = start;
    for (; j + 4 <= end; j += 4) {
        int n0 = adj[j + 0], n1 = adj[j + 1], n2 = adj[j + 2], n3 = adj[j + 3];
        acc += x[(size_t)n0 * EMB_D + coloff + d];
        acc += x[(size_t)n1 * EMB_D + coloff + d];
        acc += x[(size_t)n2 * EMB_D + coloff + d];
        acc += x[(size_t)n3 * EMB_D + coloff + d];
    }
    for (; j < end; ++j) {
        int n = adj[j];
        acc += x[(size_t)n * EMB_D + coloff + d];
    }
    halfout[(size_t)node * 32 + d] = 0.5f * acc;
}

// ---- 6) copy half buffer [N,32] into d_out columns [coloff, coloff+32) ----
__global__ __launch_bounds__(256) void k_copy_half(const float* __restrict__ half,
                                                   float* __restrict__ out,
                                                   int coloff) {
    int gid = blockIdx.x * blockDim.x + threadIdx.x;   // one per float4
    const int total = N_NODES * 32 / 4;                // 1.2M
    if (gid >= total) return;
    int node = gid >> 3;
    int q = (gid & 7) * 4;
    float4 v = *(const float4*)(half + (size_t)node * 32 + q);
    *(float4*)(out + (size_t)node * EMB_D + coloff + q) = v;
}

extern "C" void kernel_launch(void* const* d_in, const int* in_sizes, int n_in,
                              void* d_out, int out_size, void* d_ws, size_t ws_size,
                              hipStream_t stream) {
    const int*   eidx = (const int*)d_in[0];     // [2, NUM_EDGES] int32
    const float* user = (const float*)d_in[1];   // [NUM_USERS, 64]
    const float* item = (const float*)d_in[2];   // [NUM_ITEMS, 64]
    float*       out  = (float*)d_out;           // [N_NODES, 64]

    // workspace layout — total ~36.4 MB (R1 proved ws_size >= 38.4 MB)
    char* ws = (char*)d_ws;
    size_t off = 0;
    auto alloc = [&](size_t bytes) {
        char* p = ws + off;
        off += (bytes + 255) & ~(size_t)255;
        return p;
    };
    int*   adj       = (int*)alloc((size_t)4 * NUM_EDGES * sizeof(int));    // 16 MB
    int*   deg       = (int*)alloc((size_t)N_NODES * sizeof(int));          // 0.6 MB
    int*   cur       = (int*)alloc((size_t)N_NODES * sizeof(int));          // 0.6 MB
    int*   blocksums = (int*)alloc((size_t)SCAN_T * sizeof(int));
    int*   blockoffs = (int*)alloc((size_t)SCAN_T * sizeof(int));
    float* half      = (float*)alloc((size_t)N_NODES * 32 * sizeof(float)); // 19.2 MB

    hipMemsetAsync(deg, 0, (size_t)N_NODES * sizeof(int), stream);

    const int B = 256;
    const int node_grid = (N_NODES + B - 1) / B;

    // build CSR
    k_hist<<<(NUM_EDGES / 4 + B - 1) / B, B, 0, stream>>>(eidx, deg);
    k_scan_local<<<NBLK, SCAN_T, 0, stream>>>(deg, cur, blocksums);
    k_scan_partials<<<1, SCAN_T, 0, stream>>>(blocksums, blockoffs);
    k_scan_add<<<node_grid, B, 0, stream>>>(cur, blockoffs);
    k_fill<<<(NUM_EDGES / 2 + B - 1) / B, B, 0, stream>>>(eidx, cur, adj);

    // layer 1: y1 (f32) -> d_out
    const int g64 = ((N_NODES * 64) + B - 1) / B;
    k_gather64<<<g64, B, 0, stream>>>(adj, cur, deg, user, item, out);

    // layer 2, per 32-column half: gather from d_out half -> ws, copy back
    const int g32 = ((N_NODES * 32) + B - 1) / B;
    const int gcp = ((N_NODES * 32 / 4) + B - 1) / B;

    k_gather_half<<<g32, B, 0, stream>>>(adj, cur, deg, out, 0, half);
    k_copy_half<<<gcp, B, 0, stream>>>(half, out, 0);
    k_gather_half<<<g32, B, 0, stream>>>(adj, cur, deg, out, 32, half);
    k_copy_half<<<gcp, B, 0, stream>>>(half, out, 32);
}